// Round 4
// baseline (86.649 us; speedup 1.0000x reference)
//
#include <hip/hip_runtime.h>

// 4M independent 4x4 fp32 inversions (reference 2x2-block Schur formula).
// R4: barrier-free variant of R3. Each WAVE owns 64 contiguous matrices and
// a private 5KB LDS region, so the load-transpose / compute / store-transpose
// phases need no __syncthreads at all (intra-wave DS ordering is enforced by
// compiler-inserted lgkmcnt waits). Global traffic stays fully linear
// (16B/lane contiguous per wave-instruction). LDS layout 80B/matrix
// (stride 5 v4f): gather phase conflict-free, scatter <=2-way (free).
// Compute arithmetic byte-identical to R1/R3 (absmax 4096).

typedef float v4f __attribute__((ext_vector_type(4)));

__device__ __forceinline__ void inv4(const v4f r0, const v4f r1,
                                     const v4f r2, const v4f r3,
                                     v4f& o0, v4f& o1, v4f& o2, v4f& o3) {
    float a00 = r0.x, a01 = r0.y, b00 = r0.z, b01 = r0.w;
    float a10 = r1.x, a11 = r1.y, b10 = r1.z, b11 = r1.w;
    float c00 = r2.x, c01 = r2.y, d00 = r2.z, d01 = r2.w;
    float c10 = r3.x, c11 = r3.y, d10 = r3.z, d11 = r3.w;

    float adet = a00 * a11 - a01 * a10;
    float ai00 =  a11 / adet;
    float ai01 = -a01 / adet;
    float ai10 = -a10 / adet;
    float ai11 =  a00 / adet;

    float cai00 = c00 * ai00 + c01 * ai10;
    float cai01 = c00 * ai01 + c01 * ai11;
    float cai10 = c10 * ai00 + c11 * ai10;
    float cai11 = c10 * ai01 + c11 * ai11;

    float s00 = d00 - (cai00 * b00 + cai01 * b10);
    float s01 = d01 - (cai00 * b01 + cai01 * b11);
    float s10 = d10 - (cai10 * b00 + cai11 * b10);
    float s11 = d11 - (cai10 * b01 + cai11 * b11);

    float sdet = s00 * s11 - s01 * s10;
    float sc00 =  s11 / sdet;
    float sc01 = -s01 / sdet;
    float sc10 = -s10 / sdet;
    float sc11 =  s00 / sdet;

    float aib00 = ai00 * b00 + ai01 * b10;
    float aib01 = ai00 * b01 + ai01 * b11;
    float aib10 = ai10 * b00 + ai11 * b10;
    float aib11 = ai10 * b01 + ai11 * b11;

    float B00 = -(aib00 * sc00 + aib01 * sc10);
    float B01 = -(aib00 * sc01 + aib01 * sc11);
    float B10 = -(aib10 * sc00 + aib11 * sc10);
    float B11 = -(aib10 * sc01 + aib11 * sc11);

    float C00 = -(sc00 * cai00 + sc01 * cai10);
    float C01 = -(sc00 * cai01 + sc01 * cai11);
    float C10 = -(sc10 * cai00 + sc11 * cai10);
    float C11 = -(sc10 * cai01 + sc11 * cai11);

    float A00 = ai00 - (aib00 * C00 + aib01 * C10);
    float A01 = ai01 - (aib00 * C01 + aib01 * C11);
    float A10 = ai10 - (aib10 * C00 + aib11 * C10);
    float A11 = ai11 - (aib10 * C01 + aib11 * C11);

    o0 = (v4f){A00, A01, B00, B01};
    o1 = (v4f){A10, A11, B10, B11};
    o2 = (v4f){C00, C01, sc00, sc01};
    o3 = (v4f){C10, C11, sc10, sc11};
}

__global__ __launch_bounds__(256) void inv4x4_kernel(
    const float* __restrict__ x, float* __restrict__ out, int n) {
    constexpr int MPB = 256;            // matrices per block (64 per wave)
    __shared__ v4f lds[4][64 * 5];      // 5KB private region per wave -> 20KB

    const int t = threadIdx.x;
    const int w = t >> 6;               // wave id 0..3
    const int lane = t & 63;
    const long long base = (long long)blockIdx.x * MPB;

    if (base + MPB <= n) {
        // ---- fast path: wave w owns matrices [base+64w, base+64w+64) ----
        // wave-relative linear v4f index g = 64k + lane, k=0..3;
        // g maps to (matrix g>>2, row g&3).
        const v4f* __restrict__ gin =
            reinterpret_cast<const v4f*>(x) + base * 4 + w * 256;
        v4f v0 = __builtin_nontemporal_load(&gin[lane]);
        v4f v1 = __builtin_nontemporal_load(&gin[64 + lane]);
        v4f v2 = __builtin_nontemporal_load(&gin[128 + lane]);
        v4f v3 = __builtin_nontemporal_load(&gin[192 + lane]);

        v4f* __restrict__ L = lds[w];
        {
            int g;
            g = lane;       L[(g >> 2) * 5 + (g & 3)] = v0;
            g = 64 + lane;  L[(g >> 2) * 5 + (g & 3)] = v1;
            g = 128 + lane; L[(g >> 2) * 5 + (g & 3)] = v2;
            g = 192 + lane; L[(g >> 2) * 5 + (g & 3)] = v3;
        }
        // no barrier: producer and consumer are the same wave

        v4f r0 = L[lane * 5 + 0];
        v4f r1 = L[lane * 5 + 1];
        v4f r2 = L[lane * 5 + 2];
        v4f r3 = L[lane * 5 + 3];

        v4f o0, o1, o2, o3;
        inv4(r0, r1, r2, r3, o0, o1, o2, o3);

        L[lane * 5 + 0] = o0;
        L[lane * 5 + 1] = o1;
        L[lane * 5 + 2] = o2;
        L[lane * 5 + 3] = o3;

        v4f* __restrict__ gout =
            reinterpret_cast<v4f*>(out) + base * 4 + w * 256;
        {
            int g;
            g = lane;       __builtin_nontemporal_store(L[(g >> 2) * 5 + (g & 3)], &gout[g]);
            g = 64 + lane;  __builtin_nontemporal_store(L[(g >> 2) * 5 + (g & 3)], &gout[g]);
            g = 128 + lane; __builtin_nontemporal_store(L[(g >> 2) * 5 + (g & 3)], &gout[g]);
            g = 192 + lane; __builtin_nontemporal_store(L[(g >> 2) * 5 + (g & 3)], &gout[g]);
        }
    } else {
        // ---- tail path (unused for N=4,000,000, kept for safety) ----
        long long i = base + t;
        if (i < n) {
            const v4f* __restrict__ xin =
                reinterpret_cast<const v4f*>(x) + i * 4;
            v4f o0, o1, o2, o3;
            inv4(xin[0], xin[1], xin[2], xin[3], o0, o1, o2, o3);
            v4f* __restrict__ o = reinterpret_cast<v4f*>(out) + i * 4;
            o[0] = o0; o[1] = o1; o[2] = o2; o[3] = o3;
        }
    }
}

extern "C" void kernel_launch(void* const* d_in, const int* in_sizes, int n_in,
                              void* d_out, int out_size, void* d_ws, size_t ws_size,
                              hipStream_t stream) {
    const float* x = (const float*)d_in[0];
    float* out = (float*)d_out;
    int n = in_sizes[0] / 16;  // 4,000,000 matrices
    int block = 256;
    int grid = (n + block - 1) / block;
    inv4x4_kernel<<<grid, block, 0, stream>>>(x, out, n);
}

// Round 5
// 85.063 us; speedup vs baseline: 1.0186x; 1.0186x over previous
//
#include <hip/hip_runtime.h>

// 4M independent 4x4 fp32 inversions (reference 2x2-block Schur formula).
// FINAL (= R3, measured best 85.1us / 6.01 TB/s effective, 95.5% of the
// measured float4-copy ceiling 6.29 TB/s).
// Global loads/stores are fully linear 16B/lane streams; per-matrix row
// access happens in LDS with an 80B/matrix padded layout (stride 5 v4f):
// gather phase conflict-free, scatter phase <=2-way (free, m136).
// R4 ablation showed barrier removal is neutral-to-negative: the three
// __syncthreads are fully hidden by 8-blocks/CU TLP. Keep the simpler R3.
// Compute arithmetic byte-identical to R1 (absmax 4096).

typedef float v4f __attribute__((ext_vector_type(4)));

__device__ __forceinline__ void inv4(const v4f r0, const v4f r1,
                                     const v4f r2, const v4f r3,
                                     v4f& o0, v4f& o1, v4f& o2, v4f& o3) {
    float a00 = r0.x, a01 = r0.y, b00 = r0.z, b01 = r0.w;
    float a10 = r1.x, a11 = r1.y, b10 = r1.z, b11 = r1.w;
    float c00 = r2.x, c01 = r2.y, d00 = r2.z, d01 = r2.w;
    float c10 = r3.x, c11 = r3.y, d10 = r3.z, d11 = r3.w;

    float adet = a00 * a11 - a01 * a10;
    float ai00 =  a11 / adet;
    float ai01 = -a01 / adet;
    float ai10 = -a10 / adet;
    float ai11 =  a00 / adet;

    float cai00 = c00 * ai00 + c01 * ai10;
    float cai01 = c00 * ai01 + c01 * ai11;
    float cai10 = c10 * ai00 + c11 * ai10;
    float cai11 = c10 * ai01 + c11 * ai11;

    float s00 = d00 - (cai00 * b00 + cai01 * b10);
    float s01 = d01 - (cai00 * b01 + cai01 * b11);
    float s10 = d10 - (cai10 * b00 + cai11 * b10);
    float s11 = d11 - (cai10 * b01 + cai11 * b11);

    float sdet = s00 * s11 - s01 * s10;
    float sc00 =  s11 / sdet;
    float sc01 = -s01 / sdet;
    float sc10 = -s10 / sdet;
    float sc11 =  s00 / sdet;

    float aib00 = ai00 * b00 + ai01 * b10;
    float aib01 = ai00 * b01 + ai01 * b11;
    float aib10 = ai10 * b00 + ai11 * b10;
    float aib11 = ai10 * b01 + ai11 * b11;

    float B00 = -(aib00 * sc00 + aib01 * sc10);
    float B01 = -(aib00 * sc01 + aib01 * sc11);
    float B10 = -(aib10 * sc00 + aib11 * sc10);
    float B11 = -(aib10 * sc01 + aib11 * sc11);

    float C00 = -(sc00 * cai00 + sc01 * cai10);
    float C01 = -(sc00 * cai01 + sc01 * cai11);
    float C10 = -(sc10 * cai00 + sc11 * cai10);
    float C11 = -(sc10 * cai01 + sc11 * cai11);

    float A00 = ai00 - (aib00 * C00 + aib01 * C10);
    float A01 = ai01 - (aib00 * C01 + aib01 * C11);
    float A10 = ai10 - (aib10 * C00 + aib11 * C10);
    float A11 = ai11 - (aib10 * C01 + aib11 * C11);

    o0 = (v4f){A00, A01, B00, B01};
    o1 = (v4f){A10, A11, B10, B11};
    o2 = (v4f){C00, C01, sc00, sc01};
    o3 = (v4f){C10, C11, sc10, sc11};
}

__global__ __launch_bounds__(256) void inv4x4_kernel(
    const float* __restrict__ x, float* __restrict__ out, int n) {
    constexpr int MPB = 256;          // matrices per block
    __shared__ v4f lds[MPB * 5];      // 80B/matrix -> 20KB

    const int t = threadIdx.x;
    const long long base = (long long)blockIdx.x * MPB;

    if (base + MPB <= n) {
        // ---- fast path: full block of 256 matrices ----
        const v4f* __restrict__ gin =
            reinterpret_cast<const v4f*>(x) + base * 4;
        v4f v0 = __builtin_nontemporal_load(&gin[t]);
        v4f v1 = __builtin_nontemporal_load(&gin[256 + t]);
        v4f v2 = __builtin_nontemporal_load(&gin[512 + t]);
        v4f v3 = __builtin_nontemporal_load(&gin[768 + t]);

        // scatter linear v4f index f -> matrix f>>2, row f&3
        {
            int f;
            f = t;       lds[(f >> 2) * 5 + (f & 3)] = v0;
            f = 256 + t; lds[(f >> 2) * 5 + (f & 3)] = v1;
            f = 512 + t; lds[(f >> 2) * 5 + (f & 3)] = v2;
            f = 768 + t; lds[(f >> 2) * 5 + (f & 3)] = v3;
        }
        __syncthreads();

        v4f r0 = lds[t * 5 + 0];
        v4f r1 = lds[t * 5 + 1];
        v4f r2 = lds[t * 5 + 2];
        v4f r3 = lds[t * 5 + 3];

        v4f o0, o1, o2, o3;
        inv4(r0, r1, r2, r3, o0, o1, o2, o3);

        __syncthreads();               // all input reads done; reuse buffer
        lds[t * 5 + 0] = o0;
        lds[t * 5 + 1] = o1;
        lds[t * 5 + 2] = o2;
        lds[t * 5 + 3] = o3;
        __syncthreads();

        v4f* __restrict__ gout = reinterpret_cast<v4f*>(out) + base * 4;
        {
            int f;
            f = t;       __builtin_nontemporal_store(lds[(f >> 2) * 5 + (f & 3)], &gout[f]);
            f = 256 + t; __builtin_nontemporal_store(lds[(f >> 2) * 5 + (f & 3)], &gout[f]);
            f = 512 + t; __builtin_nontemporal_store(lds[(f >> 2) * 5 + (f & 3)], &gout[f]);
            f = 768 + t; __builtin_nontemporal_store(lds[(f >> 2) * 5 + (f & 3)], &gout[f]);
        }
    } else {
        // ---- tail path (unused for N=4,000,000, kept for safety) ----
        long long i = base + t;
        if (i < n) {
            const v4f* __restrict__ xin =
                reinterpret_cast<const v4f*>(x) + i * 4;
            v4f o0, o1, o2, o3;
            inv4(xin[0], xin[1], xin[2], xin[3], o0, o1, o2, o3);
            v4f* __restrict__ o = reinterpret_cast<v4f*>(out) + i * 4;
            o[0] = o0; o[1] = o1; o[2] = o2; o[3] = o3;
        }
    }
}

extern "C" void kernel_launch(void* const* d_in, const int* in_sizes, int n_in,
                              void* d_out, int out_size, void* d_ws, size_t ws_size,
                              hipStream_t stream) {
    const float* x = (const float*)d_in[0];
    float* out = (float*)d_out;
    int n = in_sizes[0] / 16;  // 4,000,000 matrices
    int block = 256;
    int grid = (n + block - 1) / block;
    inv4x4_kernel<<<grid, block, 0, stream>>>(x, out, n);
}